// Round 1
// baseline (501.636 us; speedup 1.0000x reference)
//
#include <hip/hip_runtime.h>
#include <cmath>

#define T_DIM 2048
#define B_DIM 16
#define D_DIM 256
#define RT 64
#define CT 64
#define LDP 260   // padded LDS row stride in floats (260*4=1040B, 16B-aligned)
#define TEMP_INV 10.0f
#define NEG_INF_F (-1e30f)

__global__ void init_ws_kernel(float* ws) {
    if (threadIdx.x < 32) ws[threadIdx.x] = 0.0f;
}

__global__ __launch_bounds__(256) void rowloss_kernel(
    const float* __restrict__ q1, const float* __restrict__ k2,
    const float* __restrict__ q2, const float* __restrict__ k1,
    const int* __restrict__ len_q1, const int* __restrict__ len_k2,
    const int* __restrict__ len_q2, const int* __restrict__ len_k1,
    float* __restrict__ ws_sums)
{
    const int pair = blockIdx.z;
    const int b    = blockIdx.y;
    const int t0   = blockIdx.x * RT;

    const float* pred = (pair == 0) ? q1 : q2;
    const float* targ = (pair == 0) ? k2 : k1;
    const int lp = (pair == 0) ? len_q1[b] : len_q2[b];
    const int lt = (pair == 0) ? len_k2[b] : len_k1[b];
    const int m  = min(lp, lt);
    if (t0 >= m) return;   // uniform per block: safe early exit

    __shared__ float plds[RT][LDP];
    __shared__ float tlds[CT][LDP];
    __shared__ float wsum[4];

    const int tid  = threadIdx.x;
    const int lane = tid & 63;
    const int w    = tid >> 6;
    const int tc   = tid & 15;   // column group
    const int tr   = tid >> 4;   // row group

    // ---- load pred tile: wave w loads rows i*4+w, one full 1KB row per wave-instr
    #pragma unroll
    for (int i = 0; i < 16; ++i) {
        const int row = i * 4 + w;
        const float4 v = *reinterpret_cast<const float4*>(
            &pred[(size_t)(t0 + row) * (B_DIM * D_DIM) + (size_t)b * D_DIM + lane * 4]);
        *reinterpret_cast<float4*>(&plds[row][lane * 4]) = v;
    }

    float rmax[4], rsum[4], diag[4];
    #pragma unroll
    for (int i = 0; i < 4; ++i) { rmax[i] = NEG_INF_F; rsum[i] = 0.0f; diag[i] = NEG_INF_F; }

    for (int s0 = 0; s0 < m; s0 += CT) {
        __syncthreads();  // pred stores visible; tlds safe to overwrite
        #pragma unroll
        for (int i = 0; i < 16; ++i) {
            const int row = i * 4 + w;
            const float4 v = *reinterpret_cast<const float4*>(
                &targ[(size_t)(s0 + row) * (B_DIM * D_DIM) + (size_t)b * D_DIM + lane * 4]);
            *reinterpret_cast<float4*>(&tlds[row][lane * 4]) = v;
        }
        __syncthreads();

        // ---- 64x64 dot tile, 4x4 micro-tile per thread
        float acc[4][4];
        #pragma unroll
        for (int i = 0; i < 4; ++i)
            #pragma unroll
            for (int j = 0; j < 4; ++j) acc[i][j] = 0.0f;

        for (int d = 0; d < D_DIM; d += 4) {
            float4 a[4], bb[4];
            #pragma unroll
            for (int i = 0; i < 4; ++i)
                a[i] = *reinterpret_cast<const float4*>(&plds[tr + 16 * i][d]);
            #pragma unroll
            for (int j = 0; j < 4; ++j)
                bb[j] = *reinterpret_cast<const float4*>(&tlds[tc + 16 * j][d]);
            #pragma unroll
            for (int i = 0; i < 4; ++i)
                #pragma unroll
                for (int j = 0; j < 4; ++j) {
                    acc[i][j] += a[i].x * bb[j].x;
                    acc[i][j] += a[i].y * bb[j].y;
                    acc[i][j] += a[i].z * bb[j].z;
                    acc[i][j] += a[i].w * bb[j].w;
                }
        }

        // ---- online logsumexp update per owned row
        #pragma unroll
        for (int i = 0; i < 4; ++i) {
            const int t = t0 + tr + 16 * i;
            float lg[4];
            float cmax = NEG_INF_F;
            #pragma unroll
            for (int j = 0; j < 4; ++j) {
                const int s = s0 + tc + 16 * j;
                float v = acc[i][j] * TEMP_INV;
                v = (s < m) ? v : NEG_INF_F;
                if (s == t) diag[i] = v;
                lg[j] = v;
                cmax = fmaxf(cmax, v);
            }
            // reduce max over the 16 lanes sharing this row
            #pragma unroll
            for (int msk = 1; msk < 16; msk <<= 1)
                cmax = fmaxf(cmax, __shfl_xor(cmax, msk, 64));
            const float nmax = fmaxf(rmax[i], cmax);
            float csum = 0.0f;
            #pragma unroll
            for (int j = 0; j < 4; ++j) csum += __expf(lg[j] - nmax);
            #pragma unroll
            for (int msk = 1; msk < 16; msk <<= 1)
                csum += __shfl_xor(csum, msk, 64);
            rsum[i] = rsum[i] * __expf(rmax[i] - nmax) + csum;
            rmax[i] = nmax;
        }
    }

    // ---- reduce diag across the 16-lane row group
    #pragma unroll
    for (int i = 0; i < 4; ++i)
        #pragma unroll
        for (int msk = 1; msk < 16; msk <<= 1)
            diag[i] = fmaxf(diag[i], __shfl_xor(diag[i], msk, 64));

    float local = 0.0f;
    if (tc == 0) {
        #pragma unroll
        for (int i = 0; i < 4; ++i) {
            const int t = t0 + tr + 16 * i;
            if (t < m)
                local += (__logf(rsum[i]) + rmax[i]) - diag[i];
        }
    }
    // lanes 0,16,32,48 hold partials; combine within wave
    local += __shfl_xor(local, 16, 64);
    local += __shfl_xor(local, 32, 64);
    if (lane == 0) wsum[w] = local;
    __syncthreads();
    if (tid == 0) {
        const float tot = wsum[0] + wsum[1] + wsum[2] + wsum[3];
        atomicAdd(&ws_sums[pair * B_DIM + b], tot);
    }
}

__global__ void finalize_kernel(
    const int* __restrict__ len_q1, const int* __restrict__ len_k2,
    const int* __restrict__ len_q2, const int* __restrict__ len_k1,
    const float* __restrict__ ws_sums, float* __restrict__ out)
{
    if (threadIdx.x != 0 || blockIdx.x != 0) return;
    float losses[2];
    #pragma unroll
    for (int p = 0; p < 2; ++p) {
        float tot = 0.0f, nv = 0.0f;
        for (int b = 0; b < B_DIM; ++b) {
            const int lp = (p == 0) ? len_q1[b] : len_q2[b];
            const int lt = (p == 0) ? len_k2[b] : len_k1[b];
            const int m  = min(lp, lt);
            if (m > 0) {
                tot += ws_sums[p * B_DIM + b] / (float)m;
                nv  += 1.0f;
            }
        }
        losses[p] = (nv > 0.0f) ? (tot / nv) : 0.0f;
    }
    out[0] = 0.5f * (losses[0] + losses[1]);
}

extern "C" void kernel_launch(void* const* d_in, const int* in_sizes, int n_in,
                              void* d_out, int out_size, void* d_ws, size_t ws_size,
                              hipStream_t stream) {
    const float* q1 = (const float*)d_in[0];
    const float* k2 = (const float*)d_in[1];
    const float* q2 = (const float*)d_in[2];
    const float* k1 = (const float*)d_in[3];
    const int* lq1 = (const int*)d_in[6];
    const int* lk2 = (const int*)d_in[7];
    const int* lq2 = (const int*)d_in[8];
    const int* lk1 = (const int*)d_in[9];
    float* ws  = (float*)d_ws;
    float* out = (float*)d_out;

    init_ws_kernel<<<1, 32, 0, stream>>>(ws);

    dim3 grid(T_DIM / RT, B_DIM, 2);
    rowloss_kernel<<<grid, 256, 0, stream>>>(q1, k2, q2, k1, lq1, lk2, lq2, lk1, ws);

    finalize_kernel<<<1, 64, 0, stream>>>(lq1, lk2, lq2, lk1, ws, out);
}

// Round 2
// 116.142 us; speedup vs baseline: 4.3192x; 4.3192x over previous
//
#include <hip/hip_runtime.h>
#include <hip/hip_bf16.h>
#include <cmath>

#define T_DIM 2048
#define B_DIM 16
#define D_DIM 256
#define BD (B_DIM * D_DIM)
#define BM 128
#define BN 64
#define TEMP_INV 10.0f
#define NEG_INF_F (-1e30f)

typedef __attribute__((ext_vector_type(8))) short bf16x8;
typedef __attribute__((ext_vector_type(4))) float f32x4;

static __device__ __forceinline__ ushort f2bf(float f) {
    union { float f; unsigned int u; } x; x.f = f;
    // round-to-nearest-even bf16
    unsigned int r = (x.u + 0x7FFFu + ((x.u >> 16) & 1u)) >> 16;
    return (ushort)r;
}

__global__ void init_ws_kernel(float* ws) {
    if (threadIdx.x < 32) ws[threadIdx.x] = 0.0f;
}

__global__ __launch_bounds__(256, 2) void rowloss_mfma_kernel(
    const float* __restrict__ q1, const float* __restrict__ k2,
    const float* __restrict__ q2, const float* __restrict__ k1,
    const int* __restrict__ len_q1, const int* __restrict__ len_k2,
    const int* __restrict__ len_q2, const int* __restrict__ len_k1,
    float* __restrict__ ws_sums)
{
    const int pair = blockIdx.z;
    const int b    = blockIdx.y;
    const int t0   = blockIdx.x * BM;

    const float* pred = (pair == 0) ? q1 : q2;
    const float* targ = (pair == 0) ? k2 : k1;
    const int lp = (pair == 0) ? len_q1[b] : len_q2[b];
    const int lt = (pair == 0) ? len_k2[b] : len_k1[b];
    const int m  = min(lp, lt);
    if (t0 >= m) return;   // block-uniform early exit

    __shared__ ushort tl[BN * 256];   // 64 rows x 256 bf16, XOR-swizzled = 32KB

    const int tid = threadIdx.x;
    const int w   = tid >> 6;     // wave id 0..3
    const int l   = tid & 63;     // lane
    const int c   = l & 15;       // MFMA col / row-within-16
    const int g   = l >> 4;       // lane group 0..3 (k-group / 4-row group)

    // ---- preload pred rows [t0+32w, t0+32w+32) as bf16 MFMA A-fragments in regs
    bf16x8 afrag[2][8];
    #pragma unroll
    for (int i = 0; i < 2; ++i) {
        const int trow = t0 + 32 * w + 16 * i + c;
        const float* base = &pred[(size_t)trow * BD + (size_t)b * D_DIM];
        #pragma unroll
        for (int kk = 0; kk < 8; ++kk) {
            const int d = g * 8 + kk * 32;
            const float4 v0 = *reinterpret_cast<const float4*>(base + d);
            const float4 v1 = *reinterpret_cast<const float4*>(base + d + 4);
            bf16x8 av;
            av[0] = (short)f2bf(v0.x); av[1] = (short)f2bf(v0.y);
            av[2] = (short)f2bf(v0.z); av[3] = (short)f2bf(v0.w);
            av[4] = (short)f2bf(v1.x); av[5] = (short)f2bf(v1.y);
            av[6] = (short)f2bf(v1.z); av[7] = (short)f2bf(v1.w);
            afrag[i][kk] = av;
        }
    }

    float rmax[2][4], rsum[2][4], dg[2][4];
    #pragma unroll
    for (int i = 0; i < 2; ++i)
        #pragma unroll
        for (int rr = 0; rr < 4; ++rr) {
            rmax[i][rr] = NEG_INF_F; rsum[i][rr] = 0.0f; dg[i][rr] = NEG_INF_F;
        }

    for (int s0 = 0; s0 < m; s0 += BN) {
        __syncthreads();   // previous tile's reads done before overwrite
        // ---- stage targ tile [s0, s0+64) x 256 as bf16 into swizzled LDS
        #pragma unroll
        for (int v = 0; v < 16; ++v) {
            const int f  = v * 256 + tid;
            const int r  = f >> 6;        // row in tile
            const int fc = f & 63;        // float4 index within row
            const int d0 = fc * 4;
            int sr = s0 + r; sr = (sr < T_DIM) ? sr : (T_DIM - 1);  // clamp OOB (masked later)
            const float4 vv = *reinterpret_cast<const float4*>(
                &targ[(size_t)sr * BD + (size_t)b * D_DIM + d0]);
            ushort4 h;
            h.x = f2bf(vv.x); h.y = f2bf(vv.y); h.z = f2bf(vv.z); h.w = f2bf(vv.w);
            *reinterpret_cast<ushort4*>(&tl[(r << 8) + (d0 ^ ((r & 15) << 3))]) = h;
        }
        __syncthreads();

        // ---- 32x64 logit tile per wave: acc[i][j] = pred[32w+16i..][.] . targ[16j..][.]
        f32x4 acc[2][4];
        #pragma unroll
        for (int i = 0; i < 2; ++i)
            #pragma unroll
            for (int j = 0; j < 4; ++j)
                acc[i][j] = (f32x4){0.f, 0.f, 0.f, 0.f};

        #pragma unroll
        for (int kk = 0; kk < 8; ++kk) {
            bf16x8 bfrag[4];
            #pragma unroll
            for (int j = 0; j < 4; ++j) {
                const int r = 16 * j + c;                       // targ row within tile
                const int d = g * 8 + kk * 32;
                bfrag[j] = *reinterpret_cast<const bf16x8*>(&tl[(r << 8) + (d ^ (c << 3))]);
            }
            #pragma unroll
            for (int i = 0; i < 2; ++i)
                #pragma unroll
                for (int j = 0; j < 4; ++j)
                    acc[i][j] = __builtin_amdgcn_mfma_f32_16x16x32_bf16(
                        afrag[i][kk], bfrag[j], acc[i][j], 0, 0, 0);
        }

        // ---- online logsumexp update (C layout: col = c, row = 4*g + rr within frag)
        #pragma unroll
        for (int i = 0; i < 2; ++i) {
            #pragma unroll
            for (int rr = 0; rr < 4; ++rr) {
                const int trow = t0 + 32 * w + 16 * i + 4 * g + rr;
                float lg[4];
                float cmax = NEG_INF_F;
                #pragma unroll
                for (int j = 0; j < 4; ++j) {
                    const int s = s0 + 16 * j + c;
                    float v = acc[i][j][rr] * TEMP_INV;
                    v = (s < m) ? v : NEG_INF_F;
                    if (s == trow) dg[i][rr] = v;
                    lg[j] = v;
                    cmax = fmaxf(cmax, v);
                }
                #pragma unroll
                for (int msk = 1; msk < 16; msk <<= 1)
                    cmax = fmaxf(cmax, __shfl_xor(cmax, msk, 64));
                const float nmax = fmaxf(rmax[i][rr], cmax);
                float csum = __expf(lg[0] - nmax) + __expf(lg[1] - nmax)
                           + __expf(lg[2] - nmax) + __expf(lg[3] - nmax);
                #pragma unroll
                for (int msk = 1; msk < 16; msk <<= 1)
                    csum += __shfl_xor(csum, msk, 64);
                rsum[i][rr] = rsum[i][rr] * __expf(rmax[i][rr] - nmax) + csum;
                rmax[i][rr] = nmax;
            }
        }
    }

    // ---- final: row_loss = log(rsum) + rmax - diag, rows t < m
    float local = 0.0f;
    #pragma unroll
    for (int i = 0; i < 2; ++i) {
        #pragma unroll
        for (int rr = 0; rr < 4; ++rr) {
            #pragma unroll
            for (int msk = 1; msk < 16; msk <<= 1)
                dg[i][rr] = fmaxf(dg[i][rr], __shfl_xor(dg[i][rr], msk, 64));
            const int trow = t0 + 32 * w + 16 * i + 4 * g + rr;
            if (c == 0 && trow < m)
                local += (__logf(rsum[i][rr]) + rmax[i][rr]) - dg[i][rr];
        }
    }
    local += __shfl_xor(local, 16, 64);
    local += __shfl_xor(local, 32, 64);
    if (l == 0)
        atomicAdd(&ws_sums[pair * B_DIM + b], local);
}

__global__ void finalize_kernel(
    const int* __restrict__ len_q1, const int* __restrict__ len_k2,
    const int* __restrict__ len_q2, const int* __restrict__ len_k1,
    const float* __restrict__ ws_sums, float* __restrict__ out)
{
    if (threadIdx.x != 0 || blockIdx.x != 0) return;
    float losses[2];
    #pragma unroll
    for (int p = 0; p < 2; ++p) {
        float tot = 0.0f, nv = 0.0f;
        for (int b = 0; b < B_DIM; ++b) {
            const int lp = (p == 0) ? len_q1[b] : len_q2[b];
            const int lt = (p == 0) ? len_k2[b] : len_k1[b];
            const int mm = min(lp, lt);
            if (mm > 0) {
                tot += ws_sums[p * B_DIM + b] / (float)mm;
                nv  += 1.0f;
            }
        }
        losses[p] = (nv > 0.0f) ? (tot / nv) : 0.0f;
    }
    out[0] = 0.5f * (losses[0] + losses[1]);
}

extern "C" void kernel_launch(void* const* d_in, const int* in_sizes, int n_in,
                              void* d_out, int out_size, void* d_ws, size_t ws_size,
                              hipStream_t stream) {
    const float* q1 = (const float*)d_in[0];
    const float* k2 = (const float*)d_in[1];
    const float* q2 = (const float*)d_in[2];
    const float* k1 = (const float*)d_in[3];
    const int* lq1 = (const int*)d_in[6];
    const int* lk2 = (const int*)d_in[7];
    const int* lq2 = (const int*)d_in[8];
    const int* lk1 = (const int*)d_in[9];
    float* ws  = (float*)d_ws;
    float* out = (float*)d_out;

    init_ws_kernel<<<1, 32, 0, stream>>>(ws);

    dim3 grid(T_DIM / BM, B_DIM, 2);   // 16 x 16 x 2 = 512 blocks
    rowloss_mfma_kernel<<<grid, 256, 0, stream>>>(q1, k2, q2, k1, lq1, lk2, lq2, lk1, ws);

    finalize_kernel<<<1, 64, 0, stream>>>(lq1, lk2, lq2, lk1, ws, out);
}